// Round 11
// baseline (152.055 us; speedup 1.0000x reference)
//
#include <hip/hip_runtime.h>
#include <hip/hip_bf16.h>
#include <math.h>

#define NN 20000
#define NE 320000
#define BN_EPS 1e-5f
#define CAP 48            // per-node edge-bucket capacity (max in-degree ~40 for this data)
#define CNTP 16           // cnt padding: one counter per 64B

// ---- workspace layout (total ~26.9 MB; identical to R8/R10 which passed) ----
#define MSG_BYTES   (NE * 16 * 4)            // 20,480,000  per-edge messages (non-atomic)
#define ELIST_OFF   MSG_BYTES
#define ELIST_BYTES (NN * CAP * 4)           //  3,840,000  bucketed edge ids
#define CNT_OFF     (ELIST_OFF + ELIST_BYTES)
#define CNT_BYTES   (NN * CNTP * 4)          //  1,280,000  padded in-degree counters
#define BNACC_OFF   (CNT_OFF + CNT_BYTES)    // 128 B BN accumulators
#define Y_OFF       (BNACC_OFF + 128)
// memset region: cntp + bnacc (contiguous)
#define ZERO_OFF    CNT_OFF
#define ZERO_BYTES  (CNT_BYTES + 128)

typedef _Float16 f16x8 __attribute__((ext_vector_type(8)));
typedef float    f32x4 __attribute__((ext_vector_type(4)));

union H8 { f16x8 v; unsigned short us[8]; unsigned int ui[4]; };

// native fp16 converts (v_cvt_f16_f32, RNE)
__device__ __forceinline__ unsigned short f2h(float f) {
    _Float16 h = (_Float16)f;
    return __builtin_bit_cast(unsigned short, h);
}
__device__ __forceinline__ unsigned int pack2h(float a, float b) {
    return (unsigned int)f2h(a) | ((unsigned int)f2h(b) << 16);
}

// ============================ edge path (+fused self stats) ============================
// R11 = R10 edge kernel + two latency-regime edits (R10 post-mortem: non-edge ~86us is
// harness-invariant; warm edge = 57us with all pipes <30% -> the one unhidden latency
// is efeat, consumed ~20cy after issue -> ~600-900cy exposed HBM wait per iteration):
//   - efeat prefetched 1 iteration ahead into registers (stage 2 runs with no mem wait;
//     in-order vmcnt lets the prefetch retire across the whole previous iteration)
//   - s_setprio(1) around the stage-3 MFMA cluster (independent waves, attn-like regime
//     where setprio measured +4-7%; not the lockstep-GEMM null case)
__global__ __launch_bounds__(256, 4) void edge_kernel(
    const float* __restrict__ h_neigh, const float* __restrict__ efeat,
    const int* __restrict__ src, const int* __restrict__ dst,
    const float* __restrict__ We1, const float* __restrict__ be1,
    const float* __restrict__ We2, const float* __restrict__ be2,
    float* __restrict__ msgb, int* __restrict__ elist,
    int* __restrict__ cntp,
    const float* __restrict__ h_self, const float* __restrict__ Wsf,
    float* __restrict__ y, float* __restrict__ bnacc)
{
    // A-frag-swizzled We2^T (fp16): [mb][kb][lane][j]  32 KB
    __shared__ __align__(16) unsigned short A3sw[16 * 2 * 64 * 8];
    __shared__ float red[4][32];   // self-path block reduction

    const int t = threadIdx.x;

    // ---- init A3sw from We2 (coalesced float4 reads, swizzled f16 writes)
    {
        const float4* W2v = (const float4*)We2;
#pragma unroll
        for (int it = 0; it < 16; it++) {
            int c4 = t + 256 * it;          // 0..4095 float4 chunks
            float4 w = W2v[c4];
            int f = c4 * 4;
            int h = f >> 8, c = f & 255;
            int mb = c >> 4, kb = h >> 5, hh = h & 31, co = c & 15;
            int base = ((mb * 2 + kb) * 64 + (hh >> 3) * 16) * 8 + (hh & 7);
            A3sw[base + (co + 0) * 8] = f2h(w.x);
            A3sw[base + (co + 1) * 8] = f2h(w.y);
            A3sw[base + (co + 2) * 8] = f2h(w.z);
            A3sw[base + (co + 3) * 8] = f2h(w.w);
        }
    }

    // ---- phase 0: bucket build, fully up front (zero atomics in the compute loop)
    for (int i = (int)blockIdx.x * 256 + t; i < NE; i += (int)gridDim.x * 256) {
        int d0 = dst[i];
        int k0 = atomicAdd(&cntp[d0 * CNTP], 1);
        if (k0 < CAP) elist[d0 * CAP + k0] = i;
    }
    __syncthreads();

    const int L = t & 63, wv = t >> 6;
    const int lo16 = L & 15, q = L >> 4;
    const int qc = q & 1;
    const bool qlow = (q < 2);
    const bool qhi1 = ((q >> 1) != 0);   // target-side chunk select

    // ---- hoisted A-frags for mb 0..3 (loop-invariant, 32 VGPRs)
    H8 a3r[4][2];
#pragma unroll
    for (int mb = 0; mb < 4; mb++) {
        a3r[mb][0].v = *(const f16x8*)&A3sw[((mb * 2 + 0) * 64 + L) * 8];
        a3r[mb][1].v = *(const f16x8*)&A3sw[((mb * 2 + 1) * 64 + L) * 8];
    }

    // ---- We1^T A-frag (fp16 single), bias in slot k=16
    H8 w1[4];
#pragma unroll
    for (int c = 0; c < 4; c++) {
#pragma unroll
        for (int j = 0; j < 8; j++) {
            float w;
            if (q < 2)                 w = We1[(q * 8 + j) * 64 + c * 16 + lo16];
            else if (q == 2 && j == 0) w = be1[c * 16 + lo16];
            else                       w = 0.f;
            w1[c].us[j] = f2h(w);
        }
    }

    // A-frag of be2^T (fp16)
    H8 be2T;
#pragma unroll
    for (int j = 0; j < 8; j++) {
        float bv = be2[(qc * 8 + j) * 16 + lo16];
        be2T.us[j] = qlow ? f2h(bv) : (unsigned short)0;
    }

    // bpermute source-lane byte addresses (loop-invariant)
    const int addrA = (((q & 1) * 2 + 0) * 16 + lo16) * 4;
    const int addrB = (((q & 1) * 2 + 1) * 16 + lo16) * 4;

    const int NT = NE / 64;
    int bt = blockIdx.x;
    {
        // ---- pipeline prologue: tile 0 src + efeat
        int e = bt * 64 + wv * 16 + lo16;
        int se = src[e];
        const float4* ep0 = (const float4*)(efeat + (size_t)e * 16 + qc * 8);
        float4 efA = ep0[0], efB = ep0[1];

        while (true) {
            // ---- current xr gathers first (se from prefetch; h_neigh is L2-resident)
            float xr[16];
            {
                const float4* xp = (const float4*)(h_neigh + (size_t)se * 16);
#pragma unroll
                for (int k4 = 0; k4 < 4; k4++) {
                    float4 a = xp[k4];
                    xr[k4*4+0] = a.x; xr[k4*4+1] = a.y; xr[k4*4+2] = a.z; xr[k4*4+3] = a.w;
                }
            }

            // ---- fire NEXT tile's src + efeat (retire across this iter's compute)
            int btn = bt + gridDim.x;
            bool hn = btn < NT;
            int en = 0, sen = 0;
            float4 efAn = efA, efBn = efB;
            if (hn) {
                en = btn * 64 + wv * 16 + lo16;
                sen = src[en];
                const float4* epn = (const float4*)(efeat + (size_t)en * 16 + qc * 8);
                efAn = epn[0]; efBn = epn[1];
            }

            // B-frag of ef^T (fp16 single) from PREFETCHED registers -- no memory wait;
            // bias partner 1.0 at (q==2, j==0)
            H8 a2;
            {
                float ev[8] = {efA.x, efA.y, efA.z, efA.w, efB.x, efB.y, efB.z, efB.w};
#pragma unroll
                for (int j = 0; j < 8; j++) {
                    if (qlow) {
                        a2.us[j] = f2h(ev[j]);
                    } else {
                        a2.us[j] = (q == 2 && j == 0) ? (unsigned short)0x3C00 : (unsigned short)0;
                    }
                }
            }

            // stage 2T (1 MFMA/chunk): ehT chunk c holds rows h = c*16 + q*4 + r
            float vch[4][4];
#pragma unroll
            for (int c = 0; c < 4; c++) {
                f32x4 c2 = {0.f, 0.f, 0.f, 0.f};
                c2 = __builtin_amdgcn_mfma_f32_16x16x32_f16(w1[c].v, a2.v, c2, 0, 0, 0);
#pragma unroll
                for (int r = 0; r < 4; r++) vch[c][r] = fmaxf(c2[r], 0.f);
            }

            // pack fp16 dword pairs
            unsigned int dw[4][2];
#pragma unroll
            for (int c = 0; c < 4; c++) {
#pragma unroll
                for (int d = 0; d < 2; d++)
                    dw[c][d] = pack2h(vch[c][2*d], vch[c][2*d+1]);
            }

            // pulls -> stage-3 B-frags: pull BOTH chunk candidates, select by q>>1
            H8 b3[2];
#pragma unroll
            for (int kb = 0; kb < 2; kb++) {
#pragma unroll
                for (int tt = 0; tt < 4; tt++) {
                    int d = tt & 1;
                    int addr = (tt >> 1) ? addrB : addrA;
                    int h0 = __builtin_amdgcn_ds_bpermute(addr, (int)dw[kb*2+0][d]);
                    int h1 = __builtin_amdgcn_ds_bpermute(addr, (int)dw[kb*2+1][d]);
                    b3[kb].ui[tt] = (unsigned int)(qhi1 ? h1 : h0);
                }
            }

            // be2 term: msg = be2^T @ x^T
            H8 xT;
#pragma unroll
            for (int j = 0; j < 8; j++)
                xT.us[j] = qlow ? f2h(xr[qc * 8 + j]) : (unsigned short)0;
            f32x4 msg = {0.f, 0.f, 0.f, 0.f};
            msg = __builtin_amdgcn_mfma_f32_16x16x32_f16(be2T.v, xT.v, msg, 0, 0, 0);

            // stage 3: per mb(=i): C = We2^T @ ehT, msg += x[i]*C
            // (setprio: independent waves -> scheduler favors the MFMA-entering wave)
            __builtin_amdgcn_s_setprio(1);
#pragma unroll
            for (int mb = 0; mb < 4; mb++) {
                f32x4 acc = {0.f, 0.f, 0.f, 0.f};
                acc = __builtin_amdgcn_mfma_f32_16x16x32_f16(a3r[mb][0].v, b3[0].v, acc, 0, 0, 0);
                acc = __builtin_amdgcn_mfma_f32_16x16x32_f16(a3r[mb][1].v, b3[1].v, acc, 0, 0, 0);
                float xm = xr[mb];
                msg[0] += xm * acc[0];
                msg[1] += xm * acc[1];
                msg[2] += xm * acc[2];
                msg[3] += xm * acc[3];
            }
#pragma unroll 4
            for (int mb = 4; mb < 16; mb++) {
                f16x8 a3a = *(const f16x8*)&A3sw[((mb * 2 + 0) * 64 + L) * 8];
                f16x8 a3b = *(const f16x8*)&A3sw[((mb * 2 + 1) * 64 + L) * 8];
                f32x4 acc = {0.f, 0.f, 0.f, 0.f};
                acc = __builtin_amdgcn_mfma_f32_16x16x32_f16(a3a, b3[0].v, acc, 0, 0, 0);
                acc = __builtin_amdgcn_mfma_f32_16x16x32_f16(a3b, b3[1].v, acc, 0, 0, 0);
                float xm = xr[mb];
                msg[0] += xm * acc[0];
                msg[1] += xm * acc[1];
                msg[2] += xm * acc[2];
                msg[3] += xm * acc[3];
            }
            __builtin_amdgcn_s_setprio(0);

            // ---- emit: unconditional coalesced store (overflow edges just aren't in elist)
            *(float4*)(msgb + (size_t)e * 16 + q * 4) =
                make_float4(msg[0], msg[1], msg[2], msg[3]);

            if (!hn) break;
            bt = btn; e = en; se = sen; efA = efAn; efB = efBn;
        }
    }

    // ---------------- fused self path (blocks 945..1023) ----------------
    int sb = (int)blockIdx.x - 945;
    if (sb >= 0 && sb < 79) {
        int n = sb * 256 + t;
        bool act = (n < NN);
        float hv[16], yv[16];
        if (act) {
            const float4* h4 = (const float4*)(h_self + (size_t)n * 16);
#pragma unroll
            for (int k = 0; k < 4; k++) {
                float4 a = h4[k];
                hv[4*k+0] = a.x; hv[4*k+1] = a.y; hv[4*k+2] = a.z; hv[4*k+3] = a.w;
            }
        } else {
#pragma unroll
            for (int i = 0; i < 16; i++) hv[i] = 0.f;
        }
#pragma unroll
        for (int o = 0; o < 16; o++) {
            float a = 0.f;
#pragma unroll
            for (int i = 0; i < 16; i++) a += hv[i] * Wsf[i*16 + o];
            yv[o] = a;
        }
        if (act) {
            float4* y4 = (float4*)(y + (size_t)n * 16);
#pragma unroll
            for (int k = 0; k < 4; k++)
                y4[k] = make_float4(yv[4*k+0], yv[4*k+1], yv[4*k+2], yv[4*k+3]);
        }
        int lane = t & 63;
#pragma unroll
        for (int o = 0; o < 16; o++) {
            float a = act ? yv[o] : 0.f;
            float b = act ? yv[o]*yv[o] : 0.f;
#pragma unroll
            for (int off = 32; off > 0; off >>= 1) {
                a += __shfl_down(a, off);
                b += __shfl_down(b, off);
            }
            if (lane == 0) { red[wv][o] = a; red[wv][16 + o] = b; }
        }
        __syncthreads();
        if (t < 32) {
            float s = red[0][t] + red[1][t] + red[2][t] + red[3][t];
            atomicAdd(&bnacc[t], s);
        }
    }
}

// ---- finalize: 16 threads/node: tb = n*16 + s*4 + c. Lane-quad c reads the 64B msg
// row coalesced; edge-slice s strides the bucket by 4 -> independent gathers; 1250
// blocks. shfl_xor(4/8) folds the s-slices; the s==0 quad does BN/tanh/relu/L2-norm.
__global__ __launch_bounds__(256) void final_kernel(
    const float* __restrict__ msgb, const int* __restrict__ elist,
    const int* __restrict__ cntp, const int* __restrict__ dst,
    const float* __restrict__ y, const float* __restrict__ bnacc,
    const float* __restrict__ gamma, const float* __restrict__ beta,
    float* __restrict__ out)
{
    int tb = blockIdx.x * 256 + threadIdx.x;
    int n = tb >> 4;
    if (n >= NN) return;
    int sub = tb & 15, s = sub >> 2, c = sub & 3;

    int deg = cntp[n * CNTP];
    const float4* m4 = (const float4*)msgb;

    float ax = 0.f, ay = 0.f, az = 0.f, aw = 0.f;
    if (deg <= CAP) {
        const int* el = elist + n * CAP;
        for (int k = s; k < deg; k += 4) {
            int e0 = el[k];
            float4 a0 = m4[(size_t)e0*4 + c];
            ax += a0.x; ay += a0.y; az += a0.z; aw += a0.w;
        }
    } else {
        // overflow fallback: scan every edge, slice s takes e0 % 4 == s (~never taken)
        for (int e0 = s; e0 < NE; e0 += 4) {
            if (dst[e0] == n) {
                float4 a0 = m4[(size_t)e0*4 + c];
                ax += a0.x; ay += a0.y; az += a0.z; aw += a0.w;
            }
        }
    }

    // fold the 4 edge-slices (lanes differ in bits 2..3 within the node's 16 lanes)
    ax += __shfl_xor(ax, 4); ax += __shfl_xor(ax, 8);
    ay += __shfl_xor(ay, 4); ay += __shfl_xor(ay, 8);
    az += __shfl_xor(az, 4); az += __shfl_xor(az, 8);
    aw += __shfl_xor(aw, 4); aw += __shfl_xor(aw, 8);

    if (s != 0) return;

    float4 yv4 = ((const float4*)y)[(size_t)n * 4 + c];
    float yv[4] = {yv4.x, yv4.y, yv4.z, yv4.w};
    float nb[4] = {ax, ay, az, aw};

    const float inv_n = 1.f / (float)NN;
    float z[4];
    float ss = 0.f;
#pragma unroll
    for (int r = 0; r < 4; r++) {
        int o = c * 4 + r;
        float mu  = bnacc[o] * inv_n;
        float var = bnacc[16 + o] * inv_n - mu * mu;
        float inv = rsqrtf(var + BN_EPS);
        float yy  = (yv[r] - mu) * inv * gamma[o] + beta[o];
        float tt  = tanhf(yy);
        float zz  = fmaxf(tt + nb[r], 0.f);
        z[r] = zz;
        ss += zz * zz;
    }
    // node-wide sum of squares across the 4 owning lanes (quad within one wave)
    ss += __shfl_xor(ss, 1);
    ss += __shfl_xor(ss, 2);
    float nrm = sqrtf(ss);
    if (nrm == 0.f) nrm = 1.f;
    float rr = 1.f / nrm;
    *(float4*)(out + (size_t)n * 16 + c * 4) =
        make_float4(z[0]*rr, z[1]*rr, z[2]*rr, z[3]*rr);
}

extern "C" void kernel_launch(void* const* d_in, const int* in_sizes, int n_in,
                              void* d_out, int out_size, void* d_ws, size_t ws_size,
                              hipStream_t stream) {
    const float* h_neigh = (const float*)d_in[0];
    const float* h_self  = (const float*)d_in[1];
    const float* efeat   = (const float*)d_in[2];
    const int*   src     = (const int*)d_in[3];
    const int*   dst     = (const int*)d_in[4];
    const float* W_self  = (const float*)d_in[5];
    const float* gamma   = (const float*)d_in[6];
    const float* beta    = (const float*)d_in[7];
    const float* We1     = (const float*)d_in[8];
    const float* be1     = (const float*)d_in[9];
    const float* We2     = (const float*)d_in[10];
    const float* be2     = (const float*)d_in[11];
    float* out = (float*)d_out;

    char* ws = (char*)d_ws;
    float* msgb  = (float*)ws;
    int*   elist = (int*)(ws + ELIST_OFF);
    int*   cntp  = (int*)(ws + CNT_OFF);
    float* bnacc = (float*)(ws + BNACC_OFF);
    float* y     = (float*)(ws + Y_OFF);

    // zero padded counters + BN accumulators (ws poisoned 0xAA each call)
    hipMemsetAsync(ws + ZERO_OFF, 0, ZERO_BYTES, stream);

    // 1024 blocks x 256 threads (the proven shell); blocks 945..1023 also do self path.
    edge_kernel<<<1024, 256, 0, stream>>>(
        h_neigh, efeat, src, dst, We1, be1, We2, be2,
        msgb, elist, cntp,
        h_self, W_self, y, bnacc);
    // 16 threads/node -> 1250 blocks
    final_kernel<<<(NN * 16 + 255) / 256, 256, 0, stream>>>(
        msgb, elist, cntp, dst, y, bnacc, gamma, beta, out);
}

// Round 12
// 147.119 us; speedup vs baseline: 1.0336x; 1.0336x over previous
//
#include <hip/hip_runtime.h>
#include <hip/hip_bf16.h>
#include <math.h>

#define NN 20000
#define NE 320000
#define BN_EPS 1e-5f
#define CAP 48            // per-node edge-bucket capacity (max in-degree ~40 for this data)
#define CNTP 16           // cnt padding: one counter per 64B

// ---- workspace layout (total ~26.9 MB; identical to R8/R10 which passed) ----
#define MSG_BYTES   (NE * 16 * 4)            // 20,480,000  per-edge messages (non-atomic)
#define ELIST_OFF   MSG_BYTES
#define ELIST_BYTES (NN * CAP * 4)           //  3,840,000  bucketed edge ids
#define CNT_OFF     (ELIST_OFF + ELIST_BYTES)
#define CNT_BYTES   (NN * CNTP * 4)          //  1,280,000  padded in-degree counters
#define BNACC_OFF   (CNT_OFF + CNT_BYTES)    // 128 B BN accumulators
#define Y_OFF       (BNACC_OFF + 128)
// memset region: cntp + bnacc (contiguous)
#define ZERO_OFF    CNT_OFF
#define ZERO_BYTES  (CNT_BYTES + 128)

typedef _Float16 f16x8 __attribute__((ext_vector_type(8)));
typedef float    f32x4 __attribute__((ext_vector_type(4)));

union H8 { f16x8 v; unsigned short us[8]; unsigned int ui[4]; };

// native fp16 converts (v_cvt_f16_f32, RNE)
__device__ __forceinline__ unsigned short f2h(float f) {
    _Float16 h = (_Float16)f;
    return __builtin_bit_cast(unsigned short, h);
}
__device__ __forceinline__ unsigned int pack2h(float a, float b) {
    return (unsigned int)f2h(a) | ((unsigned int)f2h(b) << 16);
}

// ============================ edge path (+fused self stats) ============================
// R12 (R11 post-mortem: efeat prefetch was right in mechanism but the +16 regs on top
// of the 32-VGPR a3r hoist tripped scratch spills -- FETCH/WRITE +23MB, edge +12%).
// Same prefetch, paid for with register budget instead of scratch:
//   - a3r hoist DROPPED (frees 32 VGPRs; costs 8 ds_read_b128 ~96 LDS-cy/wave-iter)
//   - efeat prefetched 1 iteration ahead into registers (costs 16 VGPRs; removes the
//     ~600-900cy exposed HBM wait per iteration -- the only unhidden latency left)
//   - no setprio (single-mechanism round)
// Spill gate for reading the result: FETCH ~18MB / WRITE ~39MB, VGPR <= 64.
__global__ __launch_bounds__(256, 4) void edge_kernel(
    const float* __restrict__ h_neigh, const float* __restrict__ efeat,
    const int* __restrict__ src, const int* __restrict__ dst,
    const float* __restrict__ We1, const float* __restrict__ be1,
    const float* __restrict__ We2, const float* __restrict__ be2,
    float* __restrict__ msgb, int* __restrict__ elist,
    int* __restrict__ cntp,
    const float* __restrict__ h_self, const float* __restrict__ Wsf,
    float* __restrict__ y, float* __restrict__ bnacc)
{
    // A-frag-swizzled We2^T (fp16): [mb][kb][lane][j]  32 KB
    __shared__ __align__(16) unsigned short A3sw[16 * 2 * 64 * 8];
    __shared__ float red[4][32];   // self-path block reduction

    const int t = threadIdx.x;

    // ---- init A3sw from We2 (coalesced float4 reads, swizzled f16 writes)
    {
        const float4* W2v = (const float4*)We2;
#pragma unroll
        for (int it = 0; it < 16; it++) {
            int c4 = t + 256 * it;          // 0..4095 float4 chunks
            float4 w = W2v[c4];
            int f = c4 * 4;
            int h = f >> 8, c = f & 255;
            int mb = c >> 4, kb = h >> 5, hh = h & 31, co = c & 15;
            int base = ((mb * 2 + kb) * 64 + (hh >> 3) * 16) * 8 + (hh & 7);
            A3sw[base + (co + 0) * 8] = f2h(w.x);
            A3sw[base + (co + 1) * 8] = f2h(w.y);
            A3sw[base + (co + 2) * 8] = f2h(w.z);
            A3sw[base + (co + 3) * 8] = f2h(w.w);
        }
    }

    // ---- phase 0: bucket build, fully up front (zero atomics in the compute loop)
    for (int i = (int)blockIdx.x * 256 + t; i < NE; i += (int)gridDim.x * 256) {
        int d0 = dst[i];
        int k0 = atomicAdd(&cntp[d0 * CNTP], 1);
        if (k0 < CAP) elist[d0 * CAP + k0] = i;
    }
    __syncthreads();

    const int L = t & 63, wv = t >> 6;
    const int lo16 = L & 15, q = L >> 4;
    const int qc = q & 1;
    const bool qlow = (q < 2);
    const bool qhi1 = ((q >> 1) != 0);   // target-side chunk select

    // ---- We1^T A-frag (fp16 single), bias in slot k=16
    H8 w1[4];
#pragma unroll
    for (int c = 0; c < 4; c++) {
#pragma unroll
        for (int j = 0; j < 8; j++) {
            float w;
            if (q < 2)                 w = We1[(q * 8 + j) * 64 + c * 16 + lo16];
            else if (q == 2 && j == 0) w = be1[c * 16 + lo16];
            else                       w = 0.f;
            w1[c].us[j] = f2h(w);
        }
    }

    // A-frag of be2^T (fp16)
    H8 be2T;
#pragma unroll
    for (int j = 0; j < 8; j++) {
        float bv = be2[(qc * 8 + j) * 16 + lo16];
        be2T.us[j] = qlow ? f2h(bv) : (unsigned short)0;
    }

    // bpermute source-lane byte addresses (loop-invariant)
    const int addrA = (((q & 1) * 2 + 0) * 16 + lo16) * 4;
    const int addrB = (((q & 1) * 2 + 1) * 16 + lo16) * 4;

    const int NT = NE / 64;
    int bt = blockIdx.x;
    {
        // ---- pipeline prologue: tile 0 src + efeat
        int e = bt * 64 + wv * 16 + lo16;
        int se = src[e];
        const float4* ep0 = (const float4*)(efeat + (size_t)e * 16 + qc * 8);
        float4 efA = ep0[0], efB = ep0[1];

        while (true) {
            // ---- current xr gathers first (se from prefetch; h_neigh is L2-resident)
            float xr[16];
            {
                const float4* xp = (const float4*)(h_neigh + (size_t)se * 16);
#pragma unroll
                for (int k4 = 0; k4 < 4; k4++) {
                    float4 a = xp[k4];
                    xr[k4*4+0] = a.x; xr[k4*4+1] = a.y; xr[k4*4+2] = a.z; xr[k4*4+3] = a.w;
                }
            }

            // ---- fire NEXT tile's src + efeat (retire across this iter's compute)
            int btn = bt + gridDim.x;
            bool hn = btn < NT;
            int en = 0, sen = 0;
            float4 efAn = efA, efBn = efB;
            if (hn) {
                en = btn * 64 + wv * 16 + lo16;
                sen = src[en];
                const float4* epn = (const float4*)(efeat + (size_t)en * 16 + qc * 8);
                efAn = epn[0]; efBn = epn[1];
            }

            // B-frag of ef^T (fp16 single) from PREFETCHED registers -- no memory wait;
            // bias partner 1.0 at (q==2, j==0)
            H8 a2;
            {
                float ev[8] = {efA.x, efA.y, efA.z, efA.w, efB.x, efB.y, efB.z, efB.w};
#pragma unroll
                for (int j = 0; j < 8; j++) {
                    if (qlow) {
                        a2.us[j] = f2h(ev[j]);
                    } else {
                        a2.us[j] = (q == 2 && j == 0) ? (unsigned short)0x3C00 : (unsigned short)0;
                    }
                }
            }

            // stage 2T (1 MFMA/chunk): ehT chunk c holds rows h = c*16 + q*4 + r
            float vch[4][4];
#pragma unroll
            for (int c = 0; c < 4; c++) {
                f32x4 c2 = {0.f, 0.f, 0.f, 0.f};
                c2 = __builtin_amdgcn_mfma_f32_16x16x32_f16(w1[c].v, a2.v, c2, 0, 0, 0);
#pragma unroll
                for (int r = 0; r < 4; r++) vch[c][r] = fmaxf(c2[r], 0.f);
            }

            // pack fp16 dword pairs
            unsigned int dw[4][2];
#pragma unroll
            for (int c = 0; c < 4; c++) {
#pragma unroll
                for (int d = 0; d < 2; d++)
                    dw[c][d] = pack2h(vch[c][2*d], vch[c][2*d+1]);
            }

            // pulls -> stage-3 B-frags: pull BOTH chunk candidates, select by q>>1
            H8 b3[2];
#pragma unroll
            for (int kb = 0; kb < 2; kb++) {
#pragma unroll
                for (int tt = 0; tt < 4; tt++) {
                    int d = tt & 1;
                    int addr = (tt >> 1) ? addrB : addrA;
                    int h0 = __builtin_amdgcn_ds_bpermute(addr, (int)dw[kb*2+0][d]);
                    int h1 = __builtin_amdgcn_ds_bpermute(addr, (int)dw[kb*2+1][d]);
                    b3[kb].ui[tt] = (unsigned int)(qhi1 ? h1 : h0);
                }
            }

            // be2 term: msg = be2^T @ x^T
            H8 xT;
#pragma unroll
            for (int j = 0; j < 8; j++)
                xT.us[j] = qlow ? f2h(xr[qc * 8 + j]) : (unsigned short)0;
            f32x4 msg = {0.f, 0.f, 0.f, 0.f};
            msg = __builtin_amdgcn_mfma_f32_16x16x32_f16(be2T.v, xT.v, msg, 0, 0, 0);

            // stage 3: per mb(=i): C = We2^T @ ehT, msg += x[i]*C (all frags from LDS)
#pragma unroll 4
            for (int mb = 0; mb < 16; mb++) {
                f16x8 a3a = *(const f16x8*)&A3sw[((mb * 2 + 0) * 64 + L) * 8];
                f16x8 a3b = *(const f16x8*)&A3sw[((mb * 2 + 1) * 64 + L) * 8];
                f32x4 acc = {0.f, 0.f, 0.f, 0.f};
                acc = __builtin_amdgcn_mfma_f32_16x16x32_f16(a3a, b3[0].v, acc, 0, 0, 0);
                acc = __builtin_amdgcn_mfma_f32_16x16x32_f16(a3b, b3[1].v, acc, 0, 0, 0);
                float xm = xr[mb];
                msg[0] += xm * acc[0];
                msg[1] += xm * acc[1];
                msg[2] += xm * acc[2];
                msg[3] += xm * acc[3];
            }

            // ---- emit: unconditional coalesced store (overflow edges just aren't in elist)
            *(float4*)(msgb + (size_t)e * 16 + q * 4) =
                make_float4(msg[0], msg[1], msg[2], msg[3]);

            if (!hn) break;
            bt = btn; e = en; se = sen; efA = efAn; efB = efBn;
        }
    }

    // ---------------- fused self path (blocks 945..1023) ----------------
    int sb = (int)blockIdx.x - 945;
    if (sb >= 0 && sb < 79) {
        int n = sb * 256 + t;
        bool act = (n < NN);
        float hv[16], yv[16];
        if (act) {
            const float4* h4 = (const float4*)(h_self + (size_t)n * 16);
#pragma unroll
            for (int k = 0; k < 4; k++) {
                float4 a = h4[k];
                hv[4*k+0] = a.x; hv[4*k+1] = a.y; hv[4*k+2] = a.z; hv[4*k+3] = a.w;
            }
        } else {
#pragma unroll
            for (int i = 0; i < 16; i++) hv[i] = 0.f;
        }
#pragma unroll
        for (int o = 0; o < 16; o++) {
            float a = 0.f;
#pragma unroll
            for (int i = 0; i < 16; i++) a += hv[i] * Wsf[i*16 + o];
            yv[o] = a;
        }
        if (act) {
            float4* y4 = (float4*)(y + (size_t)n * 16);
#pragma unroll
            for (int k = 0; k < 4; k++)
                y4[k] = make_float4(yv[4*k+0], yv[4*k+1], yv[4*k+2], yv[4*k+3]);
        }
        int lane = t & 63;
#pragma unroll
        for (int o = 0; o < 16; o++) {
            float a = act ? yv[o] : 0.f;
            float b = act ? yv[o]*yv[o] : 0.f;
#pragma unroll
            for (int off = 32; off > 0; off >>= 1) {
                a += __shfl_down(a, off);
                b += __shfl_down(b, off);
            }
            if (lane == 0) { red[wv][o] = a; red[wv][16 + o] = b; }
        }
        __syncthreads();
        if (t < 32) {
            float s = red[0][t] + red[1][t] + red[2][t] + red[3][t];
            atomicAdd(&bnacc[t], s);
        }
    }
}

// ---- finalize: 16 threads/node: tb = n*16 + s*4 + c. Lane-quad c reads the 64B msg
// row coalesced; edge-slice s strides the bucket by 4 -> independent gathers; 1250
// blocks. shfl_xor(4/8) folds the s-slices; the s==0 quad does BN/tanh/relu/L2-norm.
__global__ __launch_bounds__(256) void final_kernel(
    const float* __restrict__ msgb, const int* __restrict__ elist,
    const int* __restrict__ cntp, const int* __restrict__ dst,
    const float* __restrict__ y, const float* __restrict__ bnacc,
    const float* __restrict__ gamma, const float* __restrict__ beta,
    float* __restrict__ out)
{
    int tb = blockIdx.x * 256 + threadIdx.x;
    int n = tb >> 4;
    if (n >= NN) return;
    int sub = tb & 15, s = sub >> 2, c = sub & 3;

    int deg = cntp[n * CNTP];
    const float4* m4 = (const float4*)msgb;

    float ax = 0.f, ay = 0.f, az = 0.f, aw = 0.f;
    if (deg <= CAP) {
        const int* el = elist + n * CAP;
        for (int k = s; k < deg; k += 4) {
            int e0 = el[k];
            float4 a0 = m4[(size_t)e0*4 + c];
            ax += a0.x; ay += a0.y; az += a0.z; aw += a0.w;
        }
    } else {
        // overflow fallback: scan every edge, slice s takes e0 % 4 == s (~never taken)
        for (int e0 = s; e0 < NE; e0 += 4) {
            if (dst[e0] == n) {
                float4 a0 = m4[(size_t)e0*4 + c];
                ax += a0.x; ay += a0.y; az += a0.z; aw += a0.w;
            }
        }
    }

    // fold the 4 edge-slices (lanes differ in bits 2..3 within the node's 16 lanes)
    ax += __shfl_xor(ax, 4); ax += __shfl_xor(ax, 8);
    ay += __shfl_xor(ay, 4); ay += __shfl_xor(ay, 8);
    az += __shfl_xor(az, 4); az += __shfl_xor(az, 8);
    aw += __shfl_xor(aw, 4); aw += __shfl_xor(aw, 8);

    if (s != 0) return;

    float4 yv4 = ((const float4*)y)[(size_t)n * 4 + c];
    float yv[4] = {yv4.x, yv4.y, yv4.z, yv4.w};
    float nb[4] = {ax, ay, az, aw};

    const float inv_n = 1.f / (float)NN;
    float z[4];
    float ss = 0.f;
#pragma unroll
    for (int r = 0; r < 4; r++) {
        int o = c * 4 + r;
        float mu  = bnacc[o] * inv_n;
        float var = bnacc[16 + o] * inv_n - mu * mu;
        float inv = rsqrtf(var + BN_EPS);
        float yy  = (yv[r] - mu) * inv * gamma[o] + beta[o];
        float tt  = tanhf(yy);
        float zz  = fmaxf(tt + nb[r], 0.f);
        z[r] = zz;
        ss += zz * zz;
    }
    // node-wide sum of squares across the 4 owning lanes (quad within one wave)
    ss += __shfl_xor(ss, 1);
    ss += __shfl_xor(ss, 2);
    float nrm = sqrtf(ss);
    if (nrm == 0.f) nrm = 1.f;
    float rr = 1.f / nrm;
    *(float4*)(out + (size_t)n * 16 + c * 4) =
        make_float4(z[0]*rr, z[1]*rr, z[2]*rr, z[3]*rr);
}

extern "C" void kernel_launch(void* const* d_in, const int* in_sizes, int n_in,
                              void* d_out, int out_size, void* d_ws, size_t ws_size,
                              hipStream_t stream) {
    const float* h_neigh = (const float*)d_in[0];
    const float* h_self  = (const float*)d_in[1];
    const float* efeat   = (const float*)d_in[2];
    const int*   src     = (const int*)d_in[3];
    const int*   dst     = (const int*)d_in[4];
    const float* W_self  = (const float*)d_in[5];
    const float* gamma   = (const float*)d_in[6];
    const float* beta    = (const float*)d_in[7];
    const float* We1     = (const float*)d_in[8];
    const float* be1     = (const float*)d_in[9];
    const float* We2     = (const float*)d_in[10];
    const float* be2     = (const float*)d_in[11];
    float* out = (float*)d_out;

    char* ws = (char*)d_ws;
    float* msgb  = (float*)ws;
    int*   elist = (int*)(ws + ELIST_OFF);
    int*   cntp  = (int*)(ws + CNT_OFF);
    float* bnacc = (float*)(ws + BNACC_OFF);
    float* y     = (float*)(ws + Y_OFF);

    // zero padded counters + BN accumulators (ws poisoned 0xAA each call)
    hipMemsetAsync(ws + ZERO_OFF, 0, ZERO_BYTES, stream);

    // 1024 blocks x 256 threads (the proven shell); blocks 945..1023 also do self path.
    edge_kernel<<<1024, 256, 0, stream>>>(
        h_neigh, efeat, src, dst, We1, be1, We2, be2,
        msgb, elist, cntp,
        h_self, W_self, y, bnacc);
    // 16 threads/node -> 1250 blocks
    final_kernel<<<(NN * 16 + 255) / 256, 256, 0, stream>>>(
        msgb, elist, cntp, dst, y, bnacc, gamma, beta, out);
}

// Round 13
// 143.039 us; speedup vs baseline: 1.0630x; 1.0285x over previous
//
#include <hip/hip_runtime.h>
#include <hip/hip_bf16.h>
#include <math.h>

#define NN 20000
#define NE 320000
#define BN_EPS 1e-5f
#define CAP 48            // per-node edge-bucket capacity (max in-degree ~40 for this data)
#define CNTP 16           // cnt padding: one counter per 64B

// ---- workspace layout (total ~26.9 MB; identical to R8/R10/R12 which passed) ----
#define MSG_BYTES   (NE * 16 * 4)            // 20,480,000  per-edge messages (non-atomic)
#define ELIST_OFF   MSG_BYTES
#define ELIST_BYTES (NN * CAP * 4)           //  3,840,000  bucketed edge ids
#define CNT_OFF     (ELIST_OFF + ELIST_BYTES)
#define CNT_BYTES   (NN * CNTP * 4)          //  1,280,000  padded in-degree counters
#define BNACC_OFF   (CNT_OFF + CNT_BYTES)    // 128 B BN accumulators
#define Y_OFF       (BNACC_OFF + 128)
// memset region: cntp + bnacc (contiguous)
#define ZERO_OFF    CNT_OFF
#define ZERO_BYTES  (CNT_BYTES + 128)

typedef _Float16 f16x8 __attribute__((ext_vector_type(8)));
typedef float    f32x4 __attribute__((ext_vector_type(4)));

union H8 { f16x8 v; unsigned short us[8]; unsigned int ui[4]; };

// native fp16 converts (v_cvt_f16_f32, RNE)
__device__ __forceinline__ unsigned short f2h(float f) {
    _Float16 h = (_Float16)f;
    return __builtin_bit_cast(unsigned short, h);
}
__device__ __forceinline__ unsigned int pack2h(float a, float b) {
    return (unsigned int)f2h(a) | ((unsigned int)f2h(b) << 16);
}

// ============================ edge path (+fused self stats) ============================
// R13 = R12 with ONE change: conflict-free A3sw init.
// R12 post-mortem: SQ_LDS_BANK_CONFLICT = 8,504,320 BIT-CONSTANT across R8-R12 while
// loop DS volume changed 25% -> the conflicts are NOT in the loop. R7->R8 delta was
// exactly 640K = (16 bpermutes/iter halved) x 20K wave-iters x 2cy. The ~8.5M lives in
// the init's scalar ds_write_b16 pattern (64 lanes concentrated on ~2-4 banks, 16-32-way)
// = ~33K cycles/CU ~ 26% of wall, serialized on the LDS pipe at kernel start.
// Fix: each thread builds one 16B A3sw ROW in registers (8 strided dword reads of the
// L2-resident We2 column-slice + pack) and emits ONE ds_write_b128; lanes write
// consecutive 16B -> canonical conflict-free pattern. Loop/prefetch/final verbatim R12.
__global__ __launch_bounds__(256, 4) void edge_kernel(
    const float* __restrict__ h_neigh, const float* __restrict__ efeat,
    const int* __restrict__ src, const int* __restrict__ dst,
    const float* __restrict__ We1, const float* __restrict__ be1,
    const float* __restrict__ We2, const float* __restrict__ be2,
    float* __restrict__ msgb, int* __restrict__ elist,
    int* __restrict__ cntp,
    const float* __restrict__ h_self, const float* __restrict__ Wsf,
    float* __restrict__ y, float* __restrict__ bnacc)
{
    // A-frag-swizzled We2^T (fp16): row R = (mb*2+kb)*64 + L holds, at j=0..7,
    // We2[kb*32 + (L>>4)*8 + j][mb*16 + (L&15)].  32 KB.
    __shared__ __align__(16) unsigned short A3sw[16 * 2 * 64 * 8];
    __shared__ float red[4][32];   // self-path block reduction

    const int t = threadIdx.x;

    // ---- init A3sw: one b128 row write per (thread, iter); conflict-free.
    {
#pragma unroll
        for (int i = 0; i < 8; i++) {
            int R = t + 256 * i;               // 0..2047
            int co = R & 15;
            int g  = (R >> 4) & 3;
            int mbkb = R >> 6;
            int mb = mbkb >> 1, kb = mbkb & 1;
            const float* wp = We2 + (size_t)(kb * 32 + g * 8) * 256 + mb * 16 + co;
            H8 h8;
#pragma unroll
            for (int j = 0; j < 8; j++)
                h8.us[j] = f2h(wp[j * 256]);
            *(f16x8*)&A3sw[R * 8] = h8.v;
        }
    }

    // ---- phase 0: bucket build, fully up front (zero atomics in the compute loop)
    for (int i = (int)blockIdx.x * 256 + t; i < NE; i += (int)gridDim.x * 256) {
        int d0 = dst[i];
        int k0 = atomicAdd(&cntp[d0 * CNTP], 1);
        if (k0 < CAP) elist[d0 * CAP + k0] = i;
    }
    __syncthreads();

    const int L = t & 63, wv = t >> 6;
    const int lo16 = L & 15, q = L >> 4;
    const int qc = q & 1;
    const bool qlow = (q < 2);
    const bool qhi1 = ((q >> 1) != 0);   // target-side chunk select

    // ---- We1^T A-frag (fp16 single), bias in slot k=16
    H8 w1[4];
#pragma unroll
    for (int c = 0; c < 4; c++) {
#pragma unroll
        for (int j = 0; j < 8; j++) {
            float w;
            if (q < 2)                 w = We1[(q * 8 + j) * 64 + c * 16 + lo16];
            else if (q == 2 && j == 0) w = be1[c * 16 + lo16];
            else                       w = 0.f;
            w1[c].us[j] = f2h(w);
        }
    }

    // A-frag of be2^T (fp16)
    H8 be2T;
#pragma unroll
    for (int j = 0; j < 8; j++) {
        float bv = be2[(qc * 8 + j) * 16 + lo16];
        be2T.us[j] = qlow ? f2h(bv) : (unsigned short)0;
    }

    // bpermute source-lane byte addresses (loop-invariant)
    const int addrA = (((q & 1) * 2 + 0) * 16 + lo16) * 4;
    const int addrB = (((q & 1) * 2 + 1) * 16 + lo16) * 4;

    const int NT = NE / 64;
    int bt = blockIdx.x;
    {
        // ---- pipeline prologue: tile 0 src + efeat
        int e = bt * 64 + wv * 16 + lo16;
        int se = src[e];
        const float4* ep0 = (const float4*)(efeat + (size_t)e * 16 + qc * 8);
        float4 efA = ep0[0], efB = ep0[1];

        while (true) {
            // ---- current xr gathers first (se from prefetch; h_neigh is L2-resident)
            float xr[16];
            {
                const float4* xp = (const float4*)(h_neigh + (size_t)se * 16);
#pragma unroll
                for (int k4 = 0; k4 < 4; k4++) {
                    float4 a = xp[k4];
                    xr[k4*4+0] = a.x; xr[k4*4+1] = a.y; xr[k4*4+2] = a.z; xr[k4*4+3] = a.w;
                }
            }

            // ---- fire NEXT tile's src + efeat (retire across this iter's compute)
            int btn = bt + gridDim.x;
            bool hn = btn < NT;
            int en = 0, sen = 0;
            float4 efAn = efA, efBn = efB;
            if (hn) {
                en = btn * 64 + wv * 16 + lo16;
                sen = src[en];
                const float4* epn = (const float4*)(efeat + (size_t)en * 16 + qc * 8);
                efAn = epn[0]; efBn = epn[1];
            }

            // B-frag of ef^T (fp16 single) from PREFETCHED registers -- no memory wait;
            // bias partner 1.0 at (q==2, j==0)
            H8 a2;
            {
                float ev[8] = {efA.x, efA.y, efA.z, efA.w, efB.x, efB.y, efB.z, efB.w};
#pragma unroll
                for (int j = 0; j < 8; j++) {
                    if (qlow) {
                        a2.us[j] = f2h(ev[j]);
                    } else {
                        a2.us[j] = (q == 2 && j == 0) ? (unsigned short)0x3C00 : (unsigned short)0;
                    }
                }
            }

            // stage 2T (1 MFMA/chunk): ehT chunk c holds rows h = c*16 + q*4 + r
            float vch[4][4];
#pragma unroll
            for (int c = 0; c < 4; c++) {
                f32x4 c2 = {0.f, 0.f, 0.f, 0.f};
                c2 = __builtin_amdgcn_mfma_f32_16x16x32_f16(w1[c].v, a2.v, c2, 0, 0, 0);
#pragma unroll
                for (int r = 0; r < 4; r++) vch[c][r] = fmaxf(c2[r], 0.f);
            }

            // pack fp16 dword pairs
            unsigned int dw[4][2];
#pragma unroll
            for (int c = 0; c < 4; c++) {
#pragma unroll
                for (int d = 0; d < 2; d++)
                    dw[c][d] = pack2h(vch[c][2*d], vch[c][2*d+1]);
            }

            // pulls -> stage-3 B-frags: pull BOTH chunk candidates, select by q>>1
            H8 b3[2];
#pragma unroll
            for (int kb = 0; kb < 2; kb++) {
#pragma unroll
                for (int tt = 0; tt < 4; tt++) {
                    int d = tt & 1;
                    int addr = (tt >> 1) ? addrB : addrA;
                    int h0 = __builtin_amdgcn_ds_bpermute(addr, (int)dw[kb*2+0][d]);
                    int h1 = __builtin_amdgcn_ds_bpermute(addr, (int)dw[kb*2+1][d]);
                    b3[kb].ui[tt] = (unsigned int)(qhi1 ? h1 : h0);
                }
            }

            // be2 term: msg = be2^T @ x^T
            H8 xT;
#pragma unroll
            for (int j = 0; j < 8; j++)
                xT.us[j] = qlow ? f2h(xr[qc * 8 + j]) : (unsigned short)0;
            f32x4 msg = {0.f, 0.f, 0.f, 0.f};
            msg = __builtin_amdgcn_mfma_f32_16x16x32_f16(be2T.v, xT.v, msg, 0, 0, 0);

            // stage 3: per mb(=i): C = We2^T @ ehT, msg += x[i]*C (all frags from LDS)
#pragma unroll 4
            for (int mb = 0; mb < 16; mb++) {
                f16x8 a3a = *(const f16x8*)&A3sw[((mb * 2 + 0) * 64 + L) * 8];
                f16x8 a3b = *(const f16x8*)&A3sw[((mb * 2 + 1) * 64 + L) * 8];
                f32x4 acc = {0.f, 0.f, 0.f, 0.f};
                acc = __builtin_amdgcn_mfma_f32_16x16x32_f16(a3a, b3[0].v, acc, 0, 0, 0);
                acc = __builtin_amdgcn_mfma_f32_16x16x32_f16(a3b, b3[1].v, acc, 0, 0, 0);
                float xm = xr[mb];
                msg[0] += xm * acc[0];
                msg[1] += xm * acc[1];
                msg[2] += xm * acc[2];
                msg[3] += xm * acc[3];
            }

            // ---- emit: unconditional coalesced store (overflow edges just aren't in elist)
            *(float4*)(msgb + (size_t)e * 16 + q * 4) =
                make_float4(msg[0], msg[1], msg[2], msg[3]);

            if (!hn) break;
            bt = btn; e = en; se = sen; efA = efAn; efB = efBn;
        }
    }

    // ---------------- fused self path (blocks 945..1023) ----------------
    int sb = (int)blockIdx.x - 945;
    if (sb >= 0 && sb < 79) {
        int n = sb * 256 + t;
        bool act = (n < NN);
        float hv[16], yv[16];
        if (act) {
            const float4* h4 = (const float4*)(h_self + (size_t)n * 16);
#pragma unroll
            for (int k = 0; k < 4; k++) {
                float4 a = h4[k];
                hv[4*k+0] = a.x; hv[4*k+1] = a.y; hv[4*k+2] = a.z; hv[4*k+3] = a.w;
            }
        } else {
#pragma unroll
            for (int i = 0; i < 16; i++) hv[i] = 0.f;
        }
#pragma unroll
        for (int o = 0; o < 16; o++) {
            float a = 0.f;
#pragma unroll
            for (int i = 0; i < 16; i++) a += hv[i] * Wsf[i*16 + o];
            yv[o] = a;
        }
        if (act) {
            float4* y4 = (float4*)(y + (size_t)n * 16);
#pragma unroll
            for (int k = 0; k < 4; k++)
                y4[k] = make_float4(yv[4*k+0], yv[4*k+1], yv[4*k+2], yv[4*k+3]);
        }
        int lane = t & 63;
#pragma unroll
        for (int o = 0; o < 16; o++) {
            float a = act ? yv[o] : 0.f;
            float b = act ? yv[o]*yv[o] : 0.f;
#pragma unroll
            for (int off = 32; off > 0; off >>= 1) {
                a += __shfl_down(a, off);
                b += __shfl_down(b, off);
            }
            if (lane == 0) { red[wv][o] = a; red[wv][16 + o] = b; }
        }
        __syncthreads();
        if (t < 32) {
            float s = red[0][t] + red[1][t] + red[2][t] + red[3][t];
            atomicAdd(&bnacc[t], s);
        }
    }
}

// ---- finalize: 16 threads/node: tb = n*16 + s*4 + c. Lane-quad c reads the 64B msg
// row coalesced; edge-slice s strides the bucket by 4 -> independent gathers; 1250
// blocks. shfl_xor(4/8) folds the s-slices; the s==0 quad does BN/tanh/relu/L2-norm.
__global__ __launch_bounds__(256) void final_kernel(
    const float* __restrict__ msgb, const int* __restrict__ elist,
    const int* __restrict__ cntp, const int* __restrict__ dst,
    const float* __restrict__ y, const float* __restrict__ bnacc,
    const float* __restrict__ gamma, const float* __restrict__ beta,
    float* __restrict__ out)
{
    int tb = blockIdx.x * 256 + threadIdx.x;
    int n = tb >> 4;
    if (n >= NN) return;
    int sub = tb & 15, s = sub >> 2, c = sub & 3;

    int deg = cntp[n * CNTP];
    const float4* m4 = (const float4*)msgb;

    float ax = 0.f, ay = 0.f, az = 0.f, aw = 0.f;
    if (deg <= CAP) {
        const int* el = elist + n * CAP;
        for (int k = s; k < deg; k += 4) {
            int e0 = el[k];
            float4 a0 = m4[(size_t)e0*4 + c];
            ax += a0.x; ay += a0.y; az += a0.z; aw += a0.w;
        }
    } else {
        // overflow fallback: scan every edge, slice s takes e0 % 4 == s (~never taken)
        for (int e0 = s; e0 < NE; e0 += 4) {
            if (dst[e0] == n) {
                float4 a0 = m4[(size_t)e0*4 + c];
                ax += a0.x; ay += a0.y; az += a0.z; aw += a0.w;
            }
        }
    }

    // fold the 4 edge-slices (lanes differ in bits 2..3 within the node's 16 lanes)
    ax += __shfl_xor(ax, 4); ax += __shfl_xor(ax, 8);
    ay += __shfl_xor(ay, 4); ay += __shfl_xor(ay, 8);
    az += __shfl_xor(az, 4); az += __shfl_xor(az, 8);
    aw += __shfl_xor(aw, 4); aw += __shfl_xor(aw, 8);

    if (s != 0) return;

    float4 yv4 = ((const float4*)y)[(size_t)n * 4 + c];
    float yv[4] = {yv4.x, yv4.y, yv4.z, yv4.w};
    float nb[4] = {ax, ay, az, aw};

    const float inv_n = 1.f / (float)NN;
    float z[4];
    float ss = 0.f;
#pragma unroll
    for (int r = 0; r < 4; r++) {
        int o = c * 4 + r;
        float mu  = bnacc[o] * inv_n;
        float var = bnacc[16 + o] * inv_n - mu * mu;
        float inv = rsqrtf(var + BN_EPS);
        float yy  = (yv[r] - mu) * inv * gamma[o] + beta[o];
        float tt  = tanhf(yy);
        float zz  = fmaxf(tt + nb[r], 0.f);
        z[r] = zz;
        ss += zz * zz;
    }
    // node-wide sum of squares across the 4 owning lanes (quad within one wave)
    ss += __shfl_xor(ss, 1);
    ss += __shfl_xor(ss, 2);
    float nrm = sqrtf(ss);
    if (nrm == 0.f) nrm = 1.f;
    float rr = 1.f / nrm;
    *(float4*)(out + (size_t)n * 16 + c * 4) =
        make_float4(z[0]*rr, z[1]*rr, z[2]*rr, z[3]*rr);
}

extern "C" void kernel_launch(void* const* d_in, const int* in_sizes, int n_in,
                              void* d_out, int out_size, void* d_ws, size_t ws_size,
                              hipStream_t stream) {
    const float* h_neigh = (const float*)d_in[0];
    const float* h_self  = (const float*)d_in[1];
    const float* efeat   = (const float*)d_in[2];
    const int*   src     = (const int*)d_in[3];
    const int*   dst     = (const int*)d_in[4];
    const float* W_self  = (const float*)d_in[5];
    const float* gamma   = (const float*)d_in[6];
    const float* beta    = (const float*)d_in[7];
    const float* We1     = (const float*)d_in[8];
    const float* be1     = (const float*)d_in[9];
    const float* We2     = (const float*)d_in[10];
    const float* be2     = (const float*)d_in[11];
    float* out = (float*)d_out;

    char* ws = (char*)d_ws;
    float* msgb  = (float*)ws;
    int*   elist = (int*)(ws + ELIST_OFF);
    int*   cntp  = (int*)(ws + CNT_OFF);
    float* bnacc = (float*)(ws + BNACC_OFF);
    float* y     = (float*)(ws + Y_OFF);

    // zero padded counters + BN accumulators (ws poisoned 0xAA each call)
    hipMemsetAsync(ws + ZERO_OFF, 0, ZERO_BYTES, stream);

    // 1024 blocks x 256 threads (the proven shell); blocks 945..1023 also do self path.
    edge_kernel<<<1024, 256, 0, stream>>>(
        h_neigh, efeat, src, dst, We1, be1, We2, be2,
        msgb, elist, cntp,
        h_self, W_self, y, bnacc);
    // 16 threads/node -> 1250 blocks
    final_kernel<<<(NN * 16 + 255) / 256, 256, 0, stream>>>(
        msgb, elist, cntp, dst, y, bnacc, gamma, beta, out);
}